// Round 12
// baseline (24.453 us; speedup 1.0000x reference)
//
#include <hip/hip_runtime.h>

__device__ __forceinline__ float lrelu(float v) { return v >= 0.f ? v : 0.01f * v; }

__device__ __forceinline__ unsigned long long shfl_down_u64(unsigned long long v, int off, int width) {
    unsigned lo = (unsigned)(v & 0xffffffffu);
    unsigned hi = (unsigned)(v >> 32);
    lo = __shfl_down(lo, off, width);
    hi = __shfl_down(hi, off, width);
    return ((unsigned long long)hi << 32) | lo;
}
__device__ __forceinline__ unsigned long long u64min(unsigned long long a, unsigned long long b) {
    return a < b ? a : b;
}

__device__ __forceinline__ float dist16(float4 r0, float4 r1, float4 r2, float4 r3,
                                        float4 z0, float4 z1, float4 z2, float4 z3) {
    float p = 0.f, d;
    d = r0.x - z0.x; p = fmaf(d, d, p);
    d = r0.y - z0.y; p = fmaf(d, d, p);
    d = r0.z - z0.z; p = fmaf(d, d, p);
    d = r0.w - z0.w; p = fmaf(d, d, p);
    d = r1.x - z1.x; p = fmaf(d, d, p);
    d = r1.y - z1.y; p = fmaf(d, d, p);
    d = r1.z - z1.z; p = fmaf(d, d, p);
    d = r1.w - z1.w; p = fmaf(d, d, p);
    d = r2.x - z2.x; p = fmaf(d, d, p);
    d = r2.y - z2.y; p = fmaf(d, d, p);
    d = r2.z - z2.z; p = fmaf(d, d, p);
    d = r2.w - z2.w; p = fmaf(d, d, p);
    d = r3.x - z3.x; p = fmaf(d, d, p);
    d = r3.y - z3.y; p = fmaf(d, d, p);
    d = r3.z - z3.z; p = fmaf(d, d, p);
    d = r3.w - z3.w; p = fmaf(d, d, p);
    return p;
}

#define PIN4(v) asm volatile("" : "+v"(v.x), "+v"(v.y), "+v"(v.z), "+v"(v.w))

// Single fused kernel (structure validated rounds 9-11, absmax 0.0 each time).
// Round 12: decoder weights staged by ALL blocks (overlaps scan; removes serial
// finisher staging), emb k=0/1 rows pinned in VGPRs across the encode barrier
// (issue-early + no remat), z_e stored at encode time by rt==0 blocks.
__global__ __launch_bounds__(1024) void vae_mega(
    const float* __restrict__ x, const float* __restrict__ eps,
    const float* __restrict__ emb,
    const float* __restrict__ w_e0, const float* __restrict__ b_e0,
    const float* __restrict__ w_e1, const float* __restrict__ b_e1,
    const float* __restrict__ w_mu, const float* __restrict__ b_mu,
    const float* __restrict__ w_lv, const float* __restrict__ b_lv,
    const float* __restrict__ w_d,  const float* __restrict__ b_d,
    const float* __restrict__ w_d0, const float* __restrict__ b_d0,
    const float* __restrict__ w_d1, const float* __restrict__ b_d1,
    const float* __restrict__ w_d2, const float* __restrict__ b_d2,
    float* __restrict__ out,
    unsigned long long* __restrict__ wsK,   // [64 bt][4 rt] 64B lines, 4 u64 used
    unsigned int* __restrict__ wsC)         // [64 bt] counters, 64B stride
{
    const int bt   = blockIdx.x >> 2;
    const int rt   = blockIdx.x & 3;
    const int tid  = threadIdx.x;
    const int w    = tid >> 6;
    const int lane = tid & 63;

    __shared__ __align__(16) float L_wmu[3200], L_wlv[3200], L_we1[500];
    __shared__ float L_we0[10], L_be0[10], L_be1[50], L_bmu[64], L_blv[64];
    __shared__ __align__(16) float L_wd[6400], L_wd0[6000], L_wd1[1800];
    __shared__ float L_bd[100], L_bd0[60], L_bd1[30], L_wd2[30];

    __shared__ float h1s[4][52];
    __shared__ __align__(16) float zs[4][64];
    __shared__ __align__(16) float zq_s[4][64];
    __shared__ unsigned long long cand[4][16];
    __shared__ int nmin_s[4];
    __shared__ int fin_s;
    __shared__ float t0s[4][2][100];
    __shared__ float t1s[4][2][60];
    __shared__ float t2s[4][2][30];

    // ---- issue emb rows for k=0,1 immediately (pinned across encode) ----
    const int g = lane >> 2;
    const int q = lane & 3;
    const int rowBase = rt * 1024 + w * 64 + g;   // rows rowBase + k*16
    const float* rp0 = emb + (rowBase +  0) * 64 + q * 16;
    const float* rp1 = emb + (rowBase + 16) * 64 + q * 16;
    float4 ea0 = *reinterpret_cast<const float4*>(rp0 + 0);
    float4 ea1 = *reinterpret_cast<const float4*>(rp0 + 4);
    float4 ea2 = *reinterpret_cast<const float4*>(rp0 + 8);
    float4 ea3 = *reinterpret_cast<const float4*>(rp0 + 12);
    float4 eb0 = *reinterpret_cast<const float4*>(rp1 + 0);
    float4 eb1 = *reinterpret_cast<const float4*>(rp1 + 4);
    float4 eb2 = *reinterpret_cast<const float4*>(rp1 + 8);
    float4 eb3 = *reinterpret_cast<const float4*>(rp1 + 12);
    PIN4(ea0); PIN4(ea1); PIN4(ea2); PIN4(ea3);
    PIN4(eb0); PIN4(eb1); PIN4(eb2); PIN4(eb3);

    // ---- stage ALL weights (encoder + decoder), cooperative ----
    {
        const float4* s4; float4* d4;
        s4 = (const float4*)w_mu; d4 = (float4*)L_wmu;
        for (int i = tid; i < 800; i += 1024) d4[i] = s4[i];
        s4 = (const float4*)w_lv; d4 = (float4*)L_wlv;
        for (int i = tid; i < 800; i += 1024) d4[i] = s4[i];
        s4 = (const float4*)w_e1; d4 = (float4*)L_we1;
        for (int i = tid; i < 125; i += 1024) d4[i] = s4[i];
        s4 = (const float4*)w_d;  d4 = (float4*)L_wd;
        for (int i = tid; i < 1600; i += 1024) d4[i] = s4[i];
        s4 = (const float4*)w_d0; d4 = (float4*)L_wd0;
        for (int i = tid; i < 1500; i += 1024) d4[i] = s4[i];
        s4 = (const float4*)w_d1; d4 = (float4*)L_wd1;
        for (int i = tid; i < 450; i += 1024) d4[i] = s4[i];
        if (tid < 10) { L_we0[tid] = w_e0[tid]; L_be0[tid] = b_e0[tid]; }
        if (tid < 50) L_be1[tid] = b_e1[tid];
        if (tid < 64) { L_bmu[tid] = b_mu[tid]; L_blv[tid] = b_lv[tid]; }
        if (tid < 100) L_bd[tid]  = b_d[tid];
        if (tid < 60)  L_bd0[tid] = b_d0[tid];
        if (tid < 30)  { L_bd1[tid] = b_d1[tid]; L_wd2[tid] = w_d2[tid]; }
    }
    __syncthreads();

    // ---- encode: wave w<4 encodes batch bt*4+w; rt==0 writes z_e ----
    if (w < 4) {
        const int j = bt * 4 + w;
        if (lane < 50) {
            const float xv = x[j];
            float acc = L_be1[lane];
            #pragma unroll
            for (int i = 0; i < 10; ++i) {
                float h = lrelu(fmaf(xv, L_we0[i], L_be0[i]));
                acc = fmaf(h, L_we1[i * 50 + lane], acc);
            }
            h1s[w][lane] = lrelu(acc);
        }
        float mu = L_bmu[lane];
        float lv = L_blv[lane];
        #pragma unroll
        for (int i = 0; i < 50; ++i) {
            float h = h1s[w][i];
            mu = fmaf(h, L_wmu[i * 64 + lane], mu);
            lv = fmaf(h, L_wlv[i * 64 + lane], lv);
        }
        const float z = fmaf(eps[j * 64 + lane], expf(0.5f * lv), mu);
        zs[w][lane] = z;
        if (rt == 0) out[j * 64 + lane] = z;      // z_e (exactly once per batch)
    }
    __syncthreads();
    PIN4(ea0); PIN4(ea1); PIN4(ea2); PIN4(ea3);   // forbid remat after barrier
    PIN4(eb0); PIN4(eb1); PIN4(eb2); PIN4(eb3);

    // ---- scan: k-outer (k=0,1 from pinned regs; k=2,3 inline loads);
    //      keys bit-identical to rounds 10/11 ----
    float4 zr[4][4];
    #pragma unroll
    for (int t = 0; t < 4; ++t) {
        const float* zb = &zs[t][q * 16];
        zr[t][0] = *reinterpret_cast<const float4*>(zb + 0);
        zr[t][1] = *reinterpret_cast<const float4*>(zb + 4);
        zr[t][2] = *reinterpret_cast<const float4*>(zb + 8);
        zr[t][3] = *reinterpret_cast<const float4*>(zb + 12);
    }
    unsigned long long bestT[4] = {~0ull, ~0ull, ~0ull, ~0ull};
    #pragma unroll
    for (int k = 0; k < 4; ++k) {
        float4 r0, r1, r2, r3;
        if (k == 0)      { r0 = ea0; r1 = ea1; r2 = ea2; r3 = ea3; }
        else if (k == 1) { r0 = eb0; r1 = eb1; r2 = eb2; r3 = eb3; }
        else {
            const float* rp = emb + (rowBase + k * 16) * 64 + q * 16;
            r0 = *reinterpret_cast<const float4*>(rp + 0);
            r1 = *reinterpret_cast<const float4*>(rp + 4);
            r2 = *reinterpret_cast<const float4*>(rp + 8);
            r3 = *reinterpret_cast<const float4*>(rp + 12);
        }
        #pragma unroll
        for (int t = 0; t < 4; ++t) {
            float p = dist16(r0, r1, r2, r3, zr[t][0], zr[t][1], zr[t][2], zr[t][3]);
            p += __shfl_xor(p, 1);
            p += __shfl_xor(p, 2);
            // dist >= 0: float bits order-preserving; low 32 = row ->
            // first-occurrence tie-break like jnp.argmin.
            const unsigned long long key =
                ((unsigned long long)__float_as_uint(p) << 32) |
                (unsigned)(rowBase + k * 16);
            bestT[t] = u64min(bestT[t], key);
        }
    }
    #pragma unroll
    for (int t = 0; t < 4; ++t) {
        unsigned long long best = bestT[t];
        #pragma unroll
        for (int off = 32; off >= 4; off >>= 1)
            best = u64min(best, shfl_down_u64(best, off, 64));
        if (lane == 0) cand[t][w] = best;
    }
    __syncthreads();

    // ---- block reduce -> ws slots -> counter ----
    if (tid < 64) {
        const int t = tid >> 4, s = tid & 15;
        unsigned long long k = cand[t][s];
        #pragma unroll
        for (int off = 8; off > 0; off >>= 1)
            k = u64min(k, shfl_down_u64(k, off, 16));
        if (s == 0)
            atomicExch(&wsK[(bt * 4 + rt) * 8 + t], k);
        if (tid == 0) {
            __threadfence();
            const unsigned old = atomicAdd(&wsC[bt * 16], 1u);
            fin_s = ((old & 3u) == 3u);
        }
    }
    __syncthreads();
    if (!fin_s) return;

    // ================= finisher: 4 batches of this bt =================
    if (tid < 16) {                     // lane = rtIdx*4 + t
        unsigned long long k =
            atomicOr(&wsK[(bt * 4 + (tid >> 2)) * 8 + (tid & 3)], 0ull);
        k = u64min(k, shfl_down_u64(k, 8, 16));
        k = u64min(k, shfl_down_u64(k, 4, 16));
        if (tid < 4) nmin_s[tid] = (int)(k & 0xffffffffu);
    }
    __syncthreads();

    // phase A: waves 8..11 -> batch i: z_q + neighbors (z_e already stored)
    if (w >= 8 && w < 12) {
        const int i = w - 8;
        const int b = bt * 4 + i;
        const int nmin = nmin_s[i];
        const int nx = nmin >> 6, ny = nmin & 63;
        const int j = lane;
        const float zq = emb[nmin * 64 + j];
        zq_s[i][j] = zq;
        out[16384 + b * 64 + j] = zq;                     // z_q
        const int nb = 32768 + b * 320;                   // z_q_neighbors [B,5,64]
        out[nb + j] = zq;                                 // row 0: z_q
        float up = (nx < 63) ? emb[((nx + 1) * 64 + ny) * 64 + j] : 0.f;
        out[nb + 64 + j] = up;                            // row 1: up
        float dn = (nx > 0) ? emb[((nx - 1) * 64 + ny) * 64 + j] : 0.f;
        out[nb + 128 + j] = dn;                           // row 2: down
        out[nb + 192 + j] = 0.f;                          // row 3: right (faithful bug)
        float lf = (ny > 0) ? emb[(nx * 64 + (ny - 1)) * 64 + j] : 0.f;
        out[nb + 256 + j] = lf;                           // row 4: left
    }
    __syncthreads();

    // decode: waves 0..7 -> batch i = w>>1, input sel = w&1 (0=z_e, 1=z_q)
    const int di  = w >> 1;
    const int sel = w & 1;
    const bool dec = (w < 8);
    const float* zv = sel ? zq_s[di] : zs[di];

    if (dec) {
        for (int jj = lane; jj < 100; jj += 64) {
            float acc = L_bd[jj];
            #pragma unroll 16
            for (int i = 0; i < 64; ++i)
                acc = fmaf(zv[i], L_wd[i * 100 + jj], acc);
            t0s[di][sel][jj] = lrelu(acc);
        }
    }
    __syncthreads();
    if (dec && lane < 60) {
        float acc = L_bd0[lane];
        #pragma unroll 10
        for (int i = 0; i < 100; ++i)
            acc = fmaf(t0s[di][sel][i], L_wd0[i * 60 + lane], acc);
        t1s[di][sel][lane] = lrelu(acc);
    }
    __syncthreads();
    if (dec && lane < 30) {
        float acc = L_bd1[lane];
        #pragma unroll 10
        for (int i = 0; i < 60; ++i)
            acc = fmaf(t1s[di][sel][i], L_wd1[i * 30 + lane], acc);
        t2s[di][sel][lane] = lrelu(acc);
    }
    __syncthreads();
    if (dec && lane == 0) {
        float acc = b_d2[0];
        #pragma unroll
        for (int i = 0; i < 30; ++i)
            acc = fmaf(t2s[di][sel][i], L_wd2[i], acc);
        const float r = lrelu(acc);
        out[(sel ? 114944 : 114688) + bt * 4 + di] = r;   // decoder_q / decoder_e
    }
}

extern "C" void kernel_launch(void* const* d_in, const int* in_sizes, int n_in,
                              void* d_out, int out_size, void* d_ws, size_t ws_size,
                              hipStream_t stream) {
    (void)in_sizes; (void)n_in; (void)ws_size; (void)out_size;
    const float* x    = (const float*)d_in[0];
    const float* eps  = (const float*)d_in[1];
    const float* emb  = (const float*)d_in[2];
    const float* w_e0 = (const float*)d_in[3];
    const float* b_e0 = (const float*)d_in[4];
    const float* w_e1 = (const float*)d_in[5];
    const float* b_e1 = (const float*)d_in[6];
    const float* w_mu = (const float*)d_in[7];
    const float* b_mu = (const float*)d_in[8];
    const float* w_lv = (const float*)d_in[9];
    const float* b_lv = (const float*)d_in[10];
    const float* w_d  = (const float*)d_in[11];
    const float* b_d  = (const float*)d_in[12];
    const float* w_d0 = (const float*)d_in[13];
    const float* b_d0 = (const float*)d_in[14];
    const float* w_d1 = (const float*)d_in[15];
    const float* b_d1 = (const float*)d_in[16];
    const float* w_d2 = (const float*)d_in[17];
    const float* b_d2 = (const float*)d_in[18];
    float* out = (float*)d_out;
    unsigned long long* wsK = (unsigned long long*)d_ws;            // 16 KB
    unsigned int* wsC = (unsigned int*)((char*)d_ws + 65536);       // 64 counters, 64B stride

    vae_mega<<<256, 1024, 0, stream>>>(
        x, eps, emb, w_e0, b_e0, w_e1, b_e1, w_mu, b_mu, w_lv, b_lv,
        w_d, b_d, w_d0, b_d0, w_d1, b_d1, w_d2, b_d2, out, wsK, wsC);
}

// Round 13
// 20.504 us; speedup vs baseline: 1.1926x; 1.1926x over previous
//
#include <hip/hip_runtime.h>

__device__ __forceinline__ float lrelu(float v) { return v >= 0.f ? v : 0.01f * v; }

__device__ __forceinline__ unsigned long long shfl_down_u64(unsigned long long v, int off, int width) {
    unsigned lo = (unsigned)(v & 0xffffffffu);
    unsigned hi = (unsigned)(v >> 32);
    lo = __shfl_down(lo, off, width);
    hi = __shfl_down(hi, off, width);
    return ((unsigned long long)hi << 32) | lo;
}
__device__ __forceinline__ unsigned long long u64min(unsigned long long a, unsigned long long b) {
    return a < b ? a : b;
}

__device__ __forceinline__ float dist16(float4 r0, float4 r1, float4 r2, float4 r3,
                                        float4 z0, float4 z1, float4 z2, float4 z3) {
    float p = 0.f, d;
    d = r0.x - z0.x; p = fmaf(d, d, p);
    d = r0.y - z0.y; p = fmaf(d, d, p);
    d = r0.z - z0.z; p = fmaf(d, d, p);
    d = r0.w - z0.w; p = fmaf(d, d, p);
    d = r1.x - z1.x; p = fmaf(d, d, p);
    d = r1.y - z1.y; p = fmaf(d, d, p);
    d = r1.z - z1.z; p = fmaf(d, d, p);
    d = r1.w - z1.w; p = fmaf(d, d, p);
    d = r2.x - z2.x; p = fmaf(d, d, p);
    d = r2.y - z2.y; p = fmaf(d, d, p);
    d = r2.z - z2.z; p = fmaf(d, d, p);
    d = r2.w - z2.w; p = fmaf(d, d, p);
    d = r3.x - z3.x; p = fmaf(d, d, p);
    d = r3.y - z3.y; p = fmaf(d, d, p);
    d = r3.z - z3.z; p = fmaf(d, d, p);
    d = r3.w - z3.w; p = fmaf(d, d, p);
    return p;
}

// Round 13 = round 11 (best, 23.3us) + (1) threadfence -> atomic-ack ordering
// (removes buffer_wbl2 from every block's critical path), (2) dual-accumulator
// decode chains (decoder outputs only; argmin path bit-identical to r9-r11),
// (3) b_d2 staged to LDS.
__global__ __launch_bounds__(1024) void vae_mega(
    const float* __restrict__ x, const float* __restrict__ eps,
    const float* __restrict__ emb,
    const float* __restrict__ w_e0, const float* __restrict__ b_e0,
    const float* __restrict__ w_e1, const float* __restrict__ b_e1,
    const float* __restrict__ w_mu, const float* __restrict__ b_mu,
    const float* __restrict__ w_lv, const float* __restrict__ b_lv,
    const float* __restrict__ w_d,  const float* __restrict__ b_d,
    const float* __restrict__ w_d0, const float* __restrict__ b_d0,
    const float* __restrict__ w_d1, const float* __restrict__ b_d1,
    const float* __restrict__ w_d2, const float* __restrict__ b_d2,
    float* __restrict__ out,
    unsigned long long* __restrict__ wsK,   // [64 bt][4 rt] 64B lines, 4 u64 used
    unsigned int* __restrict__ wsC)         // [64 bt] counters, 64B stride
{
    const int bt   = blockIdx.x >> 2;
    const int rt   = blockIdx.x & 3;
    const int tid  = threadIdx.x;
    const int w    = tid >> 6;
    const int lane = tid & 63;

    // encoder weights (staged by every block)
    __shared__ __align__(16) float L_wmu[3200], L_wlv[3200], L_we1[500];
    __shared__ float L_we0[10], L_be0[10], L_be1[50], L_bmu[64], L_blv[64];
    // decoder weights (staged by finisher only)
    __shared__ __align__(16) float L_wd[6400], L_wd0[6000], L_wd1[1800];
    __shared__ float L_bd[100], L_bd0[60], L_bd1[30], L_wd2[30], L_bd2v;

    __shared__ float h1s[4][52];
    __shared__ __align__(16) float zs[4][64];
    __shared__ __align__(16) float zq_s[4][64];
    __shared__ unsigned long long cand[4][16];
    __shared__ int nmin_s[4];
    __shared__ int fin_s;
    __shared__ float t0s[4][2][100];
    __shared__ float t1s[4][2][60];
    __shared__ float t2s[4][2][30];

    // ---- stage encoder weights (cooperative, vectorized, pipelined) ----
    {
        const float4* s4; float4* d4;
        s4 = (const float4*)w_mu; d4 = (float4*)L_wmu;
        for (int i = tid; i < 800; i += 1024) d4[i] = s4[i];
        s4 = (const float4*)w_lv; d4 = (float4*)L_wlv;
        for (int i = tid; i < 800; i += 1024) d4[i] = s4[i];
        s4 = (const float4*)w_e1; d4 = (float4*)L_we1;
        for (int i = tid; i < 125; i += 1024) d4[i] = s4[i];
        if (tid < 10) { L_we0[tid] = w_e0[tid]; L_be0[tid] = b_e0[tid]; }
        if (tid < 50) L_be1[tid] = b_e1[tid];
        if (tid < 64) { L_bmu[tid] = b_mu[tid]; L_blv[tid] = b_lv[tid]; }
    }
    __syncthreads();

    // ---- encode: wave w<4 encodes batch bt*4+w (bit-identical to r9-r11) ----
    if (w < 4) {
        const int j = bt * 4 + w;
        if (lane < 50) {
            const float xv = x[j];
            float acc = L_be1[lane];
            #pragma unroll
            for (int i = 0; i < 10; ++i) {
                float h = lrelu(fmaf(xv, L_we0[i], L_be0[i]));
                acc = fmaf(h, L_we1[i * 50 + lane], acc);
            }
            h1s[w][lane] = lrelu(acc);
        }
        float mu = L_bmu[lane];
        float lv = L_blv[lane];
        for (int i = 0; i < 50; ++i) {
            float h = h1s[w][i];
            mu = fmaf(h, L_wmu[i * 64 + lane], mu);
            lv = fmaf(h, L_wlv[i * 64 + lane], lv);
        }
        zs[w][lane] = fmaf(eps[j * 64 + lane], expf(0.5f * lv), mu);
    }
    __syncthreads();

    // ---- scan: k-outer, bit-identical keys to rounds 10/11 ----
    const int g = lane >> 2;
    const int q = lane & 3;
    const int rowBase = rt * 1024 + w * 64 + g;   // rows rowBase + k*16

    float4 zr[4][4];
    #pragma unroll
    for (int t = 0; t < 4; ++t) {
        const float* zb = &zs[t][q * 16];
        zr[t][0] = *reinterpret_cast<const float4*>(zb + 0);
        zr[t][1] = *reinterpret_cast<const float4*>(zb + 4);
        zr[t][2] = *reinterpret_cast<const float4*>(zb + 8);
        zr[t][3] = *reinterpret_cast<const float4*>(zb + 12);
    }
    unsigned long long bestT[4] = {~0ull, ~0ull, ~0ull, ~0ull};
    #pragma unroll
    for (int k = 0; k < 4; ++k) {
        const float* rp = emb + (rowBase + k * 16) * 64 + q * 16;
        const float4 r0 = *reinterpret_cast<const float4*>(rp + 0);
        const float4 r1 = *reinterpret_cast<const float4*>(rp + 4);
        const float4 r2 = *reinterpret_cast<const float4*>(rp + 8);
        const float4 r3 = *reinterpret_cast<const float4*>(rp + 12);
        #pragma unroll
        for (int t = 0; t < 4; ++t) {
            float p = dist16(r0, r1, r2, r3, zr[t][0], zr[t][1], zr[t][2], zr[t][3]);
            p += __shfl_xor(p, 1);
            p += __shfl_xor(p, 2);
            // dist >= 0: float bits order-preserving; low 32 = row ->
            // first-occurrence tie-break like jnp.argmin.
            const unsigned long long key =
                ((unsigned long long)__float_as_uint(p) << 32) |
                (unsigned)(rowBase + k * 16);
            bestT[t] = u64min(bestT[t], key);
        }
    }
    #pragma unroll
    for (int t = 0; t < 4; ++t) {
        unsigned long long best = bestT[t];
        #pragma unroll
        for (int off = 32; off >= 4; off >>= 1)
            best = u64min(best, shfl_down_u64(best, off, 64));
        if (lane == 0) cand[t][w] = best;
    }
    __syncthreads();

    // ---- block reduce -> ws slots -> counter (atomic-ack ordering: the
    //      returned 'old' forces a vmcnt wait, so all 4 exchs are complete at
    //      the coherence point before tid0's counter atomicAdd issues) ----
    if (tid < 64) {
        const int t = tid >> 4, s = tid & 15;
        unsigned long long k = cand[t][s];
        #pragma unroll
        for (int off = 8; off > 0; off >>= 1)
            k = u64min(k, shfl_down_u64(k, off, 16));
        if (s == 0) {
            unsigned long long old = atomicExch(&wsK[(bt * 4 + rt) * 8 + t], k);
            asm volatile("" :: "v"(old));     // keep result -> wait for ack
        }
        if (tid == 0) {
            const unsigned oldc = atomicAdd(&wsC[bt * 16], 1u);
            fin_s = ((oldc & 3u) == 3u);
        }
    }
    __syncthreads();
    if (!fin_s) return;

    // ================= finisher: 4 batches of this bt =================
    if (tid < 16) {                     // lane = rtIdx*4 + t
        unsigned long long k =
            atomicOr(&wsK[(bt * 4 + (tid >> 2)) * 8 + (tid & 3)], 0ull);
        k = u64min(k, shfl_down_u64(k, 8, 16));
        k = u64min(k, shfl_down_u64(k, 4, 16));
        if (tid < 4) nmin_s[tid] = (int)(k & 0xffffffffu);
    }
    // stage decoder weights (independent of nmin; all threads, overlapped)
    {
        const float4* s4; float4* d4;
        s4 = (const float4*)w_d;  d4 = (float4*)L_wd;
        for (int i = tid; i < 1600; i += 1024) d4[i] = s4[i];
        s4 = (const float4*)w_d0; d4 = (float4*)L_wd0;
        for (int i = tid; i < 1500; i += 1024) d4[i] = s4[i];
        s4 = (const float4*)w_d1; d4 = (float4*)L_wd1;
        for (int i = tid; i < 450; i += 1024) d4[i] = s4[i];
        if (tid < 100) L_bd[tid]  = b_d[tid];
        if (tid < 60)  L_bd0[tid] = b_d0[tid];
        if (tid < 30)  { L_bd1[tid] = b_d1[tid]; L_wd2[tid] = w_d2[tid]; }
        if (tid == 127) L_bd2v = b_d2[0];
    }
    __syncthreads();

    // phase A: waves 8..11 -> batch i: z_e out, z_q, neighbors
    if (w >= 8 && w < 12) {
        const int i = w - 8;
        const int b = bt * 4 + i;
        const int nmin = nmin_s[i];
        const int nx = nmin >> 6, ny = nmin & 63;
        const int j = lane;
        out[b * 64 + j] = zs[i][j];                       // z_e
        const float zq = emb[nmin * 64 + j];
        zq_s[i][j] = zq;
        out[16384 + b * 64 + j] = zq;                     // z_q
        const int nb = 32768 + b * 320;                   // z_q_neighbors [B,5,64]
        out[nb + j] = zq;                                 // row 0: z_q
        float up = (nx < 63) ? emb[((nx + 1) * 64 + ny) * 64 + j] : 0.f;
        out[nb + 64 + j] = up;                            // row 1: up
        float dn = (nx > 0) ? emb[((nx - 1) * 64 + ny) * 64 + j] : 0.f;
        out[nb + 128 + j] = dn;                           // row 2: down
        out[nb + 192 + j] = 0.f;                          // row 3: right (faithful bug)
        float lf = (ny > 0) ? emb[(nx * 64 + (ny - 1)) * 64 + j] : 0.f;
        out[nb + 256 + j] = lf;                           // row 4: left
    }
    __syncthreads();

    // decode: waves 0..7 -> batch i = w>>1, input sel = w&1 (0=z_e, 1=z_q).
    // Dual accumulators: halves the serial fma dep chain. Only decoder
    // outputs change (within ~1ulp); threshold slack is ~9e-2.
    const int di  = w >> 1;
    const int sel = w & 1;
    const bool dec = (w < 8);
    const float* zv = sel ? zq_s[di] : zs[di];

    if (dec) {
        for (int jj = lane; jj < 100; jj += 64) {
            float a0 = L_bd[jj], a1 = 0.f;
            #pragma unroll
            for (int i = 0; i < 64; i += 2) {
                a0 = fmaf(zv[i],     L_wd[i * 100 + jj],       a0);
                a1 = fmaf(zv[i + 1], L_wd[(i + 1) * 100 + jj], a1);
            }
            t0s[di][sel][jj] = lrelu(a0 + a1);
        }
    }
    __syncthreads();
    if (dec && lane < 60) {
        float a0 = L_bd0[lane], a1 = 0.f;
        #pragma unroll
        for (int i = 0; i < 100; i += 2) {
            a0 = fmaf(t0s[di][sel][i],     L_wd0[i * 60 + lane],       a0);
            a1 = fmaf(t0s[di][sel][i + 1], L_wd0[(i + 1) * 60 + lane], a1);
        }
        t1s[di][sel][lane] = lrelu(a0 + a1);
    }
    __syncthreads();
    if (dec && lane < 30) {
        float a0 = L_bd1[lane], a1 = 0.f;
        #pragma unroll
        for (int i = 0; i < 60; i += 2) {
            a0 = fmaf(t1s[di][sel][i],     L_wd1[i * 30 + lane],       a0);
            a1 = fmaf(t1s[di][sel][i + 1], L_wd1[(i + 1) * 30 + lane], a1);
        }
        t2s[di][sel][lane] = lrelu(a0 + a1);
    }
    __syncthreads();
    if (dec && lane == 0) {
        float a0 = L_bd2v, a1 = 0.f;
        #pragma unroll
        for (int i = 0; i < 30; i += 2) {
            a0 = fmaf(t2s[di][sel][i],     L_wd2[i],     a0);
            a1 = fmaf(t2s[di][sel][i + 1], L_wd2[i + 1], a1);
        }
        const float r = lrelu(a0 + a1);
        out[(sel ? 114944 : 114688) + bt * 4 + di] = r;   // decoder_q / decoder_e
    }
}

extern "C" void kernel_launch(void* const* d_in, const int* in_sizes, int n_in,
                              void* d_out, int out_size, void* d_ws, size_t ws_size,
                              hipStream_t stream) {
    (void)in_sizes; (void)n_in; (void)ws_size; (void)out_size;
    const float* x    = (const float*)d_in[0];
    const float* eps  = (const float*)d_in[1];
    const float* emb  = (const float*)d_in[2];
    const float* w_e0 = (const float*)d_in[3];
    const float* b_e0 = (const float*)d_in[4];
    const float* w_e1 = (const float*)d_in[5];
    const float* b_e1 = (const float*)d_in[6];
    const float* w_mu = (const float*)d_in[7];
    const float* b_mu = (const float*)d_in[8];
    const float* w_lv = (const float*)d_in[9];
    const float* b_lv = (const float*)d_in[10];
    const float* w_d  = (const float*)d_in[11];
    const float* b_d  = (const float*)d_in[12];
    const float* w_d0 = (const float*)d_in[13];
    const float* b_d0 = (const float*)d_in[14];
    const float* w_d1 = (const float*)d_in[15];
    const float* b_d1 = (const float*)d_in[16];
    const float* w_d2 = (const float*)d_in[17];
    const float* b_d2 = (const float*)d_in[18];
    float* out = (float*)d_out;
    unsigned long long* wsK = (unsigned long long*)d_ws;            // 16 KB
    unsigned int* wsC = (unsigned int*)((char*)d_ws + 65536);       // 64 counters, 64B stride

    vae_mega<<<256, 1024, 0, stream>>>(
        x, eps, emb, w_e0, b_e0, w_e1, b_e1, w_mu, b_mu, w_lv, b_lv,
        w_d, b_d, w_d0, b_d0, w_d1, b_d1, w_d2, b_d2, out, wsK, wsC);
}

// Round 14
// 20.431 us; speedup vs baseline: 1.1968x; 1.0036x over previous
//
#include <hip/hip_runtime.h>

__device__ __forceinline__ float lrelu(float v) { return v >= 0.f ? v : 0.01f * v; }

__device__ __forceinline__ unsigned long long shfl_down_u64(unsigned long long v, int off, int width) {
    unsigned lo = (unsigned)(v & 0xffffffffu);
    unsigned hi = (unsigned)(v >> 32);
    lo = __shfl_down(lo, off, width);
    hi = __shfl_down(hi, off, width);
    return ((unsigned long long)hi << 32) | lo;
}
__device__ __forceinline__ unsigned long long u64min(unsigned long long a, unsigned long long b) {
    return a < b ? a : b;
}

__device__ __forceinline__ float dist16(float4 r0, float4 r1, float4 r2, float4 r3,
                                        float4 z0, float4 z1, float4 z2, float4 z3) {
    float p = 0.f, d;
    d = r0.x - z0.x; p = fmaf(d, d, p);
    d = r0.y - z0.y; p = fmaf(d, d, p);
    d = r0.z - z0.z; p = fmaf(d, d, p);
    d = r0.w - z0.w; p = fmaf(d, d, p);
    d = r1.x - z1.x; p = fmaf(d, d, p);
    d = r1.y - z1.y; p = fmaf(d, d, p);
    d = r1.z - z1.z; p = fmaf(d, d, p);
    d = r1.w - z1.w; p = fmaf(d, d, p);
    d = r2.x - z2.x; p = fmaf(d, d, p);
    d = r2.y - z2.y; p = fmaf(d, d, p);
    d = r2.z - z2.z; p = fmaf(d, d, p);
    d = r2.w - z2.w; p = fmaf(d, d, p);
    d = r3.x - z3.x; p = fmaf(d, d, p);
    d = r3.y - z3.y; p = fmaf(d, d, p);
    d = r3.z - z3.z; p = fmaf(d, d, p);
    d = r3.w - z3.w; p = fmaf(d, d, p);
    return p;
}

// Round 14 = round 13 (best, 20.5us) + decode_e offloaded to rt==0 blocks
// (decoder_e depends only on z_e, not argmin -> runs concurrent with other
// blocks' scans), z_e written at encode time. Finisher tail = keys + z_q +
// neighbors + decode_q only. Argmin path bit-identical to r9-r13.
__global__ __launch_bounds__(1024) void vae_mega(
    const float* __restrict__ x, const float* __restrict__ eps,
    const float* __restrict__ emb,
    const float* __restrict__ w_e0, const float* __restrict__ b_e0,
    const float* __restrict__ w_e1, const float* __restrict__ b_e1,
    const float* __restrict__ w_mu, const float* __restrict__ b_mu,
    const float* __restrict__ w_lv, const float* __restrict__ b_lv,
    const float* __restrict__ w_d,  const float* __restrict__ b_d,
    const float* __restrict__ w_d0, const float* __restrict__ b_d0,
    const float* __restrict__ w_d1, const float* __restrict__ b_d1,
    const float* __restrict__ w_d2, const float* __restrict__ b_d2,
    float* __restrict__ out,
    unsigned long long* __restrict__ wsK,   // [64 bt][4 rt] 64B lines, 4 u64 used
    unsigned int* __restrict__ wsC)         // [64 bt] counters, 64B stride
{
    const int bt   = blockIdx.x >> 2;
    const int rt   = blockIdx.x & 3;
    const int tid  = threadIdx.x;
    const int w    = tid >> 6;
    const int lane = tid & 63;

    __shared__ __align__(16) float L_wmu[3200], L_wlv[3200], L_we1[500];
    __shared__ float L_we0[10], L_be0[10], L_be1[50], L_bmu[64], L_blv[64];
    __shared__ __align__(16) float L_wd[6400], L_wd0[6000], L_wd1[1800];
    __shared__ float L_bd[100], L_bd0[60], L_bd1[30], L_wd2[30], L_bd2v;

    __shared__ float h1s[4][52];
    __shared__ __align__(16) float zs[4][64];
    __shared__ __align__(16) float zq_s[4][64];
    __shared__ unsigned long long cand[4][16];
    __shared__ int nmin_s[4];
    __shared__ int fin_s;
    __shared__ float t0s[4][2][100];
    __shared__ float t1s[4][2][60];
    __shared__ float t2s[4][2][30];

    // ---- stage encoder weights (cooperative, vectorized, pipelined) ----
    {
        const float4* s4; float4* d4;
        s4 = (const float4*)w_mu; d4 = (float4*)L_wmu;
        for (int i = tid; i < 800; i += 1024) d4[i] = s4[i];
        s4 = (const float4*)w_lv; d4 = (float4*)L_wlv;
        for (int i = tid; i < 800; i += 1024) d4[i] = s4[i];
        s4 = (const float4*)w_e1; d4 = (float4*)L_we1;
        for (int i = tid; i < 125; i += 1024) d4[i] = s4[i];
        if (tid < 10) { L_we0[tid] = w_e0[tid]; L_be0[tid] = b_e0[tid]; }
        if (tid < 50) L_be1[tid] = b_e1[tid];
        if (tid < 64) { L_bmu[tid] = b_mu[tid]; L_blv[tid] = b_lv[tid]; }
    }
    __syncthreads();

    // ---- encode: wave w<4 encodes batch bt*4+w; rt==0 writes z_e out ----
    if (w < 4) {
        const int j = bt * 4 + w;
        if (lane < 50) {
            const float xv = x[j];
            float acc = L_be1[lane];
            #pragma unroll
            for (int i = 0; i < 10; ++i) {
                float h = lrelu(fmaf(xv, L_we0[i], L_be0[i]));
                acc = fmaf(h, L_we1[i * 50 + lane], acc);
            }
            h1s[w][lane] = lrelu(acc);
        }
        float mu = L_bmu[lane];
        float lv = L_blv[lane];
        for (int i = 0; i < 50; ++i) {
            float h = h1s[w][i];
            mu = fmaf(h, L_wmu[i * 64 + lane], mu);
            lv = fmaf(h, L_wlv[i * 64 + lane], lv);
        }
        const float z = fmaf(eps[j * 64 + lane], expf(0.5f * lv), mu);
        zs[w][lane] = z;
        if (rt == 0) out[j * 64 + lane] = z;      // z_e (exactly once per batch)
    }
    __syncthreads();

    // ---- scan: k-outer, bit-identical keys to rounds 10-13 ----
    const int g = lane >> 2;
    const int q = lane & 3;
    const int rowBase = rt * 1024 + w * 64 + g;   // rows rowBase + k*16

    float4 zr[4][4];
    #pragma unroll
    for (int t = 0; t < 4; ++t) {
        const float* zb = &zs[t][q * 16];
        zr[t][0] = *reinterpret_cast<const float4*>(zb + 0);
        zr[t][1] = *reinterpret_cast<const float4*>(zb + 4);
        zr[t][2] = *reinterpret_cast<const float4*>(zb + 8);
        zr[t][3] = *reinterpret_cast<const float4*>(zb + 12);
    }
    unsigned long long bestT[4] = {~0ull, ~0ull, ~0ull, ~0ull};
    #pragma unroll
    for (int k = 0; k < 4; ++k) {
        const float* rp = emb + (rowBase + k * 16) * 64 + q * 16;
        const float4 r0 = *reinterpret_cast<const float4*>(rp + 0);
        const float4 r1 = *reinterpret_cast<const float4*>(rp + 4);
        const float4 r2 = *reinterpret_cast<const float4*>(rp + 8);
        const float4 r3 = *reinterpret_cast<const float4*>(rp + 12);
        #pragma unroll
        for (int t = 0; t < 4; ++t) {
            float p = dist16(r0, r1, r2, r3, zr[t][0], zr[t][1], zr[t][2], zr[t][3]);
            p += __shfl_xor(p, 1);
            p += __shfl_xor(p, 2);
            // dist >= 0: float bits order-preserving; low 32 = row ->
            // first-occurrence tie-break like jnp.argmin.
            const unsigned long long key =
                ((unsigned long long)__float_as_uint(p) << 32) |
                (unsigned)(rowBase + k * 16);
            bestT[t] = u64min(bestT[t], key);
        }
    }
    #pragma unroll
    for (int t = 0; t < 4; ++t) {
        unsigned long long best = bestT[t];
        #pragma unroll
        for (int off = 32; off >= 4; off >>= 1)
            best = u64min(best, shfl_down_u64(best, off, 64));
        if (lane == 0) cand[t][w] = best;
    }
    __syncthreads();

    // ---- block reduce -> ws slots -> counter (atomic-ack ordering) ----
    if (tid < 64) {
        const int t = tid >> 4, s = tid & 15;
        unsigned long long k = cand[t][s];
        #pragma unroll
        for (int off = 8; off > 0; off >>= 1)
            k = u64min(k, shfl_down_u64(k, off, 16));
        if (s == 0) {
            unsigned long long old = atomicExch(&wsK[(bt * 4 + rt) * 8 + t], k);
            asm volatile("" :: "v"(old));     // keep result -> wait for ack
        }
        if (tid == 0) {
            const unsigned oldc = atomicAdd(&wsC[bt * 16], 1u);
            fin_s = ((oldc & 3u) == 3u);
        }
    }
    __syncthreads();
    const bool isFin = (fin_s != 0);
    if (!isFin && rt != 0) return;       // rt==0 continues for decode_e

    // ---- finisher: read keys (device-scope) -> nmin ----
    if (isFin && tid < 16) {             // lane = rtIdx*4 + t
        unsigned long long k =
            atomicOr(&wsK[(bt * 4 + (tid >> 2)) * 8 + (tid & 3)], 0ull);
        k = u64min(k, shfl_down_u64(k, 8, 16));
        k = u64min(k, shfl_down_u64(k, 4, 16));
        if (tid < 4) nmin_s[tid] = (int)(k & 0xffffffffu);
    }
    // ---- stage decoder weights (rt==0 and/or finisher blocks) ----
    {
        const float4* s4; float4* d4;
        s4 = (const float4*)w_d;  d4 = (float4*)L_wd;
        for (int i = tid; i < 1600; i += 1024) d4[i] = s4[i];
        s4 = (const float4*)w_d0; d4 = (float4*)L_wd0;
        for (int i = tid; i < 1500; i += 1024) d4[i] = s4[i];
        s4 = (const float4*)w_d1; d4 = (float4*)L_wd1;
        for (int i = tid; i < 450; i += 1024) d4[i] = s4[i];
        if (tid < 100) L_bd[tid]  = b_d[tid];
        if (tid < 60)  L_bd0[tid] = b_d0[tid];
        if (tid < 30)  { L_bd1[tid] = b_d1[tid]; L_wd2[tid] = w_d2[tid]; }
        if (tid == 127) L_bd2v = b_d2[0];
    }
    __syncthreads();

    // phase A (finisher): waves 8..11 -> batch i: z_q + neighbors
    if (isFin && w >= 8 && w < 12) {
        const int i = w - 8;
        const int b = bt * 4 + i;
        const int nmin = nmin_s[i];
        const int nx = nmin >> 6, ny = nmin & 63;
        const int j = lane;
        const float zq = emb[nmin * 64 + j];
        zq_s[i][j] = zq;
        out[16384 + b * 64 + j] = zq;                     // z_q
        const int nb = 32768 + b * 320;                   // z_q_neighbors [B,5,64]
        out[nb + j] = zq;                                 // row 0: z_q
        float up = (nx < 63) ? emb[((nx + 1) * 64 + ny) * 64 + j] : 0.f;
        out[nb + 64 + j] = up;                            // row 1: up
        float dn = (nx > 0) ? emb[((nx - 1) * 64 + ny) * 64 + j] : 0.f;
        out[nb + 128 + j] = dn;                           // row 2: down
        out[nb + 192 + j] = 0.f;                          // row 3: right (faithful bug)
        float lf = (ny > 0) ? emb[(nx * 64 + (ny - 1)) * 64 + j] : 0.f;
        out[nb + 256 + j] = lf;                           // row 4: left
    }
    __syncthreads();

    // decode: rt==0 waves 0-3 -> decode_e (di=w, sel=0);
    //         finisher waves 4-7 -> decode_q (di=w-4, sel=1).
    // Dual accumulators (r13-validated). Disjoint [di][sel] buffers.
    const bool dec_e = (rt == 0) && (w < 4);
    const bool dec_q = isFin && (w >= 4) && (w < 8);
    const bool dec   = dec_e || dec_q;
    const int  di    = dec_e ? w : (w - 4);
    const int  sel   = dec_q ? 1 : 0;
    const float* zv  = dec_q ? zq_s[di] : zs[di];

    if (dec) {
        for (int jj = lane; jj < 100; jj += 64) {
            float a0 = L_bd[jj], a1 = 0.f;
            #pragma unroll
            for (int i = 0; i < 64; i += 2) {
                a0 = fmaf(zv[i],     L_wd[i * 100 + jj],       a0);
                a1 = fmaf(zv[i + 1], L_wd[(i + 1) * 100 + jj], a1);
            }
            t0s[di][sel][jj] = lrelu(a0 + a1);
        }
    }
    __syncthreads();
    if (dec && lane < 60) {
        float a0 = L_bd0[lane], a1 = 0.f;
        #pragma unroll
        for (int i = 0; i < 100; i += 2) {
            a0 = fmaf(t0s[di][sel][i],     L_wd0[i * 60 + lane],       a0);
            a1 = fmaf(t0s[di][sel][i + 1], L_wd0[(i + 1) * 60 + lane], a1);
        }
        t1s[di][sel][lane] = lrelu(a0 + a1);
    }
    __syncthreads();
    if (dec && lane < 30) {
        float a0 = L_bd1[lane], a1 = 0.f;
        #pragma unroll
        for (int i = 0; i < 60; i += 2) {
            a0 = fmaf(t1s[di][sel][i],     L_wd1[i * 30 + lane],       a0);
            a1 = fmaf(t1s[di][sel][i + 1], L_wd1[(i + 1) * 30 + lane], a1);
        }
        t2s[di][sel][lane] = lrelu(a0 + a1);
    }
    __syncthreads();
    if (dec && lane == 0) {
        float a0 = L_bd2v, a1 = 0.f;
        #pragma unroll
        for (int i = 0; i < 30; i += 2) {
            a0 = fmaf(t2s[di][sel][i],     L_wd2[i],     a0);
            a1 = fmaf(t2s[di][sel][i + 1], L_wd2[i + 1], a1);
        }
        const float r = lrelu(a0 + a1);
        out[(sel ? 114944 : 114688) + bt * 4 + di] = r;   // decoder_q / decoder_e
    }
}

extern "C" void kernel_launch(void* const* d_in, const int* in_sizes, int n_in,
                              void* d_out, int out_size, void* d_ws, size_t ws_size,
                              hipStream_t stream) {
    (void)in_sizes; (void)n_in; (void)ws_size; (void)out_size;
    const float* x    = (const float*)d_in[0];
    const float* eps  = (const float*)d_in[1];
    const float* emb  = (const float*)d_in[2];
    const float* w_e0 = (const float*)d_in[3];
    const float* b_e0 = (const float*)d_in[4];
    const float* w_e1 = (const float*)d_in[5];
    const float* b_e1 = (const float*)d_in[6];
    const float* w_mu = (const float*)d_in[7];
    const float* b_mu = (const float*)d_in[8];
    const float* w_lv = (const float*)d_in[9];
    const float* b_lv = (const float*)d_in[10];
    const float* w_d  = (const float*)d_in[11];
    const float* b_d  = (const float*)d_in[12];
    const float* w_d0 = (const float*)d_in[13];
    const float* b_d0 = (const float*)d_in[14];
    const float* w_d1 = (const float*)d_in[15];
    const float* b_d1 = (const float*)d_in[16];
    const float* w_d2 = (const float*)d_in[17];
    const float* b_d2 = (const float*)d_in[18];
    float* out = (float*)d_out;
    unsigned long long* wsK = (unsigned long long*)d_ws;            // 16 KB
    unsigned int* wsC = (unsigned int*)((char*)d_ws + 65536);       // 64 counters, 64B stride

    vae_mega<<<256, 1024, 0, stream>>>(
        x, eps, emb, w_e0, b_e0, w_e1, b_e1, w_mu, b_mu, w_lv, b_lv,
        w_d, b_d, w_d0, b_d0, w_d1, b_d1, w_d2, b_d2, out, wsK, wsC);
}

// Round 15
// 19.966 us; speedup vs baseline: 1.2247x; 1.0233x over previous
//
#include <hip/hip_runtime.h>

__device__ __forceinline__ float lrelu(float v) { return v >= 0.f ? v : 0.01f * v; }

__device__ __forceinline__ unsigned long long shfl_down_u64(unsigned long long v, int off, int width) {
    unsigned lo = (unsigned)(v & 0xffffffffu);
    unsigned hi = (unsigned)(v >> 32);
    lo = __shfl_down(lo, off, width);
    hi = __shfl_down(hi, off, width);
    return ((unsigned long long)hi << 32) | lo;
}
__device__ __forceinline__ unsigned long long u64min(unsigned long long a, unsigned long long b) {
    return a < b ? a : b;
}

__device__ __forceinline__ float dist16(float4 r0, float4 r1, float4 r2, float4 r3,
                                        float4 z0, float4 z1, float4 z2, float4 z3) {
    float p = 0.f, d;
    d = r0.x - z0.x; p = fmaf(d, d, p);
    d = r0.y - z0.y; p = fmaf(d, d, p);
    d = r0.z - z0.z; p = fmaf(d, d, p);
    d = r0.w - z0.w; p = fmaf(d, d, p);
    d = r1.x - z1.x; p = fmaf(d, d, p);
    d = r1.y - z1.y; p = fmaf(d, d, p);
    d = r1.z - z1.z; p = fmaf(d, d, p);
    d = r1.w - z1.w; p = fmaf(d, d, p);
    d = r2.x - z2.x; p = fmaf(d, d, p);
    d = r2.y - z2.y; p = fmaf(d, d, p);
    d = r2.z - z2.z; p = fmaf(d, d, p);
    d = r2.w - z2.w; p = fmaf(d, d, p);
    d = r3.x - z3.x; p = fmaf(d, d, p);
    d = r3.y - z3.y; p = fmaf(d, d, p);
    d = r3.z - z3.z; p = fmaf(d, d, p);
    d = r3.w - z3.w; p = fmaf(d, d, p);
    return p;
}

// Round 15 = round 14 + ONE isolated change: decoder weights staged by ALL
// blocks, placed after the scan and executed by waves 1-15 (tid>=64), so the
// staging hides in the shadow of wave 0's block-reduce atomic roundtrips and
// the finisher tail starts with weights already in LDS.
// Argmin path bit-identical to r9-r14 (absmax 0.0 each round).
__global__ __launch_bounds__(1024) void vae_mega(
    const float* __restrict__ x, const float* __restrict__ eps,
    const float* __restrict__ emb,
    const float* __restrict__ w_e0, const float* __restrict__ b_e0,
    const float* __restrict__ w_e1, const float* __restrict__ b_e1,
    const float* __restrict__ w_mu, const float* __restrict__ b_mu,
    const float* __restrict__ w_lv, const float* __restrict__ b_lv,
    const float* __restrict__ w_d,  const float* __restrict__ b_d,
    const float* __restrict__ w_d0, const float* __restrict__ b_d0,
    const float* __restrict__ w_d1, const float* __restrict__ b_d1,
    const float* __restrict__ w_d2, const float* __restrict__ b_d2,
    float* __restrict__ out,
    unsigned long long* __restrict__ wsK,   // [64 bt][4 rt] 64B lines, 4 u64 used
    unsigned int* __restrict__ wsC)         // [64 bt] counters, 64B stride
{
    const int bt   = blockIdx.x >> 2;
    const int rt   = blockIdx.x & 3;
    const int tid  = threadIdx.x;
    const int w    = tid >> 6;
    const int lane = tid & 63;

    __shared__ __align__(16) float L_wmu[3200], L_wlv[3200], L_we1[500];
    __shared__ float L_we0[10], L_be0[10], L_be1[50], L_bmu[64], L_blv[64];
    __shared__ __align__(16) float L_wd[6400], L_wd0[6000], L_wd1[1800];
    __shared__ float L_bd[100], L_bd0[60], L_bd1[30], L_wd2[30], L_bd2v;

    __shared__ float h1s[4][52];
    __shared__ __align__(16) float zs[4][64];
    __shared__ __align__(16) float zq_s[4][64];
    __shared__ unsigned long long cand[4][16];
    __shared__ int nmin_s[4];
    __shared__ int fin_s;
    __shared__ float t0s[4][2][100];
    __shared__ float t1s[4][2][60];
    __shared__ float t2s[4][2][30];

    // ---- stage encoder weights (cooperative, vectorized, pipelined) ----
    {
        const float4* s4; float4* d4;
        s4 = (const float4*)w_mu; d4 = (float4*)L_wmu;
        for (int i = tid; i < 800; i += 1024) d4[i] = s4[i];
        s4 = (const float4*)w_lv; d4 = (float4*)L_wlv;
        for (int i = tid; i < 800; i += 1024) d4[i] = s4[i];
        s4 = (const float4*)w_e1; d4 = (float4*)L_we1;
        for (int i = tid; i < 125; i += 1024) d4[i] = s4[i];
        if (tid < 10) { L_we0[tid] = w_e0[tid]; L_be0[tid] = b_e0[tid]; }
        if (tid < 50) L_be1[tid] = b_e1[tid];
        if (tid < 64) { L_bmu[tid] = b_mu[tid]; L_blv[tid] = b_lv[tid]; }
    }
    __syncthreads();

    // ---- encode: wave w<4 encodes batch bt*4+w; rt==0 writes z_e out ----
    if (w < 4) {
        const int j = bt * 4 + w;
        if (lane < 50) {
            const float xv = x[j];
            float acc = L_be1[lane];
            #pragma unroll
            for (int i = 0; i < 10; ++i) {
                float h = lrelu(fmaf(xv, L_we0[i], L_be0[i]));
                acc = fmaf(h, L_we1[i * 50 + lane], acc);
            }
            h1s[w][lane] = lrelu(acc);
        }
        float mu = L_bmu[lane];
        float lv = L_blv[lane];
        for (int i = 0; i < 50; ++i) {
            float h = h1s[w][i];
            mu = fmaf(h, L_wmu[i * 64 + lane], mu);
            lv = fmaf(h, L_wlv[i * 64 + lane], lv);
        }
        const float z = fmaf(eps[j * 64 + lane], expf(0.5f * lv), mu);
        zs[w][lane] = z;
        if (rt == 0) out[j * 64 + lane] = z;      // z_e (exactly once per batch)
    }
    __syncthreads();

    // ---- scan: k-outer, bit-identical keys to rounds 10-14 ----
    const int g = lane >> 2;
    const int q = lane & 3;
    const int rowBase = rt * 1024 + w * 64 + g;   // rows rowBase + k*16

    float4 zr[4][4];
    #pragma unroll
    for (int t = 0; t < 4; ++t) {
        const float* zb = &zs[t][q * 16];
        zr[t][0] = *reinterpret_cast<const float4*>(zb + 0);
        zr[t][1] = *reinterpret_cast<const float4*>(zb + 4);
        zr[t][2] = *reinterpret_cast<const float4*>(zb + 8);
        zr[t][3] = *reinterpret_cast<const float4*>(zb + 12);
    }
    unsigned long long bestT[4] = {~0ull, ~0ull, ~0ull, ~0ull};
    #pragma unroll
    for (int k = 0; k < 4; ++k) {
        const float* rp = emb + (rowBase + k * 16) * 64 + q * 16;
        const float4 r0 = *reinterpret_cast<const float4*>(rp + 0);
        const float4 r1 = *reinterpret_cast<const float4*>(rp + 4);
        const float4 r2 = *reinterpret_cast<const float4*>(rp + 8);
        const float4 r3 = *reinterpret_cast<const float4*>(rp + 12);
        #pragma unroll
        for (int t = 0; t < 4; ++t) {
            float p = dist16(r0, r1, r2, r3, zr[t][0], zr[t][1], zr[t][2], zr[t][3]);
            p += __shfl_xor(p, 1);
            p += __shfl_xor(p, 2);
            // dist >= 0: float bits order-preserving; low 32 = row ->
            // first-occurrence tie-break like jnp.argmin.
            const unsigned long long key =
                ((unsigned long long)__float_as_uint(p) << 32) |
                (unsigned)(rowBase + k * 16);
            bestT[t] = u64min(bestT[t], key);
        }
    }
    #pragma unroll
    for (int t = 0; t < 4; ++t) {
        unsigned long long best = bestT[t];
        #pragma unroll
        for (int off = 32; off >= 4; off >>= 1)
            best = u64min(best, shfl_down_u64(best, off, 64));
        if (lane == 0) cand[t][w] = best;
    }
    __syncthreads();

    // ---- decoder staging (waves 1-15) in the shadow of wave 0's atomics ----
    if (tid >= 64) {
        const int id = tid - 64;                  // 960 threads
        const float4* s4; float4* d4;
        s4 = (const float4*)w_d;  d4 = (float4*)L_wd;
        for (int i = id; i < 1600; i += 960) d4[i] = s4[i];
        s4 = (const float4*)w_d0; d4 = (float4*)L_wd0;
        for (int i = id; i < 1500; i += 960) d4[i] = s4[i];
        s4 = (const float4*)w_d1; d4 = (float4*)L_wd1;
        for (int i = id; i < 450; i += 960) d4[i] = s4[i];
        if (id < 100) L_bd[id]  = b_d[id];
        if (id >= 100 && id < 160) L_bd0[id - 100] = b_d0[id - 100];
        if (id >= 160 && id < 190) L_bd1[id - 160] = b_d1[id - 160];
        if (id >= 190 && id < 220) L_wd2[id - 190] = w_d2[id - 190];
        if (id == 220) L_bd2v = b_d2[0];
    }
    // ---- block reduce -> ws slots -> counter (wave 0; atomic-ack ordering) ----
    if (tid < 64) {
        const int t = tid >> 4, s = tid & 15;
        unsigned long long k = cand[t][s];
        #pragma unroll
        for (int off = 8; off > 0; off >>= 1)
            k = u64min(k, shfl_down_u64(k, off, 16));
        if (s == 0) {
            unsigned long long old = atomicExch(&wsK[(bt * 4 + rt) * 8 + t], k);
            asm volatile("" :: "v"(old));     // keep result -> wait for ack
        }
        if (tid == 0) {
            const unsigned oldc = atomicAdd(&wsC[bt * 16], 1u);
            fin_s = ((oldc & 3u) == 3u);
        }
    }
    __syncthreads();
    const bool isFin = (fin_s != 0);
    if (!isFin && rt != 0) return;       // rt==0 continues for decode_e

    // ---- finisher: read keys (device-scope) -> nmin ----
    if (isFin && tid < 16) {             // lane = rtIdx*4 + t
        unsigned long long k =
            atomicOr(&wsK[(bt * 4 + (tid >> 2)) * 8 + (tid & 3)], 0ull);
        k = u64min(k, shfl_down_u64(k, 8, 16));
        k = u64min(k, shfl_down_u64(k, 4, 16));
        if (tid < 4) nmin_s[tid] = (int)(k & 0xffffffffu);
    }
    __syncthreads();

    // phase A (finisher): waves 8..11 -> batch i: z_q + neighbors
    if (isFin && w >= 8 && w < 12) {
        const int i = w - 8;
        const int b = bt * 4 + i;
        const int nmin = nmin_s[i];
        const int nx = nmin >> 6, ny = nmin & 63;
        const int j = lane;
        const float zq = emb[nmin * 64 + j];
        zq_s[i][j] = zq;
        out[16384 + b * 64 + j] = zq;                     // z_q
        const int nb = 32768 + b * 320;                   // z_q_neighbors [B,5,64]
        out[nb + j] = zq;                                 // row 0: z_q
        float up = (nx < 63) ? emb[((nx + 1) * 64 + ny) * 64 + j] : 0.f;
        out[nb + 64 + j] = up;                            // row 1: up
        float dn = (nx > 0) ? emb[((nx - 1) * 64 + ny) * 64 + j] : 0.f;
        out[nb + 128 + j] = dn;                           // row 2: down
        out[nb + 192 + j] = 0.f;                          // row 3: right (faithful bug)
        float lf = (ny > 0) ? emb[(nx * 64 + (ny - 1)) * 64 + j] : 0.f;
        out[nb + 256 + j] = lf;                           // row 4: left
    }
    __syncthreads();

    // decode: rt==0 waves 0-3 -> decode_e (di=w, sel=0);
    //         finisher waves 4-7 -> decode_q (di=w-4, sel=1).
    // Dual accumulators (r13-validated). Disjoint [di][sel] buffers.
    const bool dec_e = (rt == 0) && (w < 4);
    const bool dec_q = isFin && (w >= 4) && (w < 8);
    const bool dec   = dec_e || dec_q;
    const int  di    = dec_e ? w : (w - 4);
    const int  sel   = dec_q ? 1 : 0;
    const float* zv  = dec_q ? zq_s[di] : zs[di];

    if (dec) {
        for (int jj = lane; jj < 100; jj += 64) {
            float a0 = L_bd[jj], a1 = 0.f;
            #pragma unroll
            for (int i = 0; i < 64; i += 2) {
                a0 = fmaf(zv[i],     L_wd[i * 100 + jj],       a0);
                a1 = fmaf(zv[i + 1], L_wd[(i + 1) * 100 + jj], a1);
            }
            t0s[di][sel][jj] = lrelu(a0 + a1);
        }
    }
    __syncthreads();
    if (dec && lane < 60) {
        float a0 = L_bd0[lane], a1 = 0.f;
        #pragma unroll
        for (int i = 0; i < 100; i += 2) {
            a0 = fmaf(t0s[di][sel][i],     L_wd0[i * 60 + lane],       a0);
            a1 = fmaf(t0s[di][sel][i + 1], L_wd0[(i + 1) * 60 + lane], a1);
        }
        t1s[di][sel][lane] = lrelu(a0 + a1);
    }
    __syncthreads();
    if (dec && lane < 30) {
        float a0 = L_bd1[lane], a1 = 0.f;
        #pragma unroll
        for (int i = 0; i < 60; i += 2) {
            a0 = fmaf(t1s[di][sel][i],     L_wd1[i * 30 + lane],       a0);
            a1 = fmaf(t1s[di][sel][i + 1], L_wd1[(i + 1) * 30 + lane], a1);
        }
        t2s[di][sel][lane] = lrelu(a0 + a1);
    }
    __syncthreads();
    if (dec && lane == 0) {
        float a0 = L_bd2v, a1 = 0.f;
        #pragma unroll
        for (int i = 0; i < 30; i += 2) {
            a0 = fmaf(t2s[di][sel][i],     L_wd2[i],     a0);
            a1 = fmaf(t2s[di][sel][i + 1], L_wd2[i + 1], a1);
        }
        const float r = lrelu(a0 + a1);
        out[(sel ? 114944 : 114688) + bt * 4 + di] = r;   // decoder_q / decoder_e
    }
}

extern "C" void kernel_launch(void* const* d_in, const int* in_sizes, int n_in,
                              void* d_out, int out_size, void* d_ws, size_t ws_size,
                              hipStream_t stream) {
    (void)in_sizes; (void)n_in; (void)ws_size; (void)out_size;
    const float* x    = (const float*)d_in[0];
    const float* eps  = (const float*)d_in[1];
    const float* emb  = (const float*)d_in[2];
    const float* w_e0 = (const float*)d_in[3];
    const float* b_e0 = (const float*)d_in[4];
    const float* w_e1 = (const float*)d_in[5];
    const float* b_e1 = (const float*)d_in[6];
    const float* w_mu = (const float*)d_in[7];
    const float* b_mu = (const float*)d_in[8];
    const float* w_lv = (const float*)d_in[9];
    const float* b_lv = (const float*)d_in[10];
    const float* w_d  = (const float*)d_in[11];
    const float* b_d  = (const float*)d_in[12];
    const float* w_d0 = (const float*)d_in[13];
    const float* b_d0 = (const float*)d_in[14];
    const float* w_d1 = (const float*)d_in[15];
    const float* b_d1 = (const float*)d_in[16];
    const float* w_d2 = (const float*)d_in[17];
    const float* b_d2 = (const float*)d_in[18];
    float* out = (float*)d_out;
    unsigned long long* wsK = (unsigned long long*)d_ws;            // 16 KB
    unsigned int* wsC = (unsigned int*)((char*)d_ws + 65536);       // 64 counters, 64B stride

    vae_mega<<<256, 1024, 0, stream>>>(
        x, eps, emb, w_e0, b_e0, w_e1, b_e1, w_mu, b_mu, w_lv, b_lv,
        w_d, b_d, w_d0, b_d0, w_d1, b_d1, w_d2, b_d2, out, wsK, wsC);
}